// Round 1
// baseline (1014.573 us; speedup 1.0000x reference)
//
#include <hip/hip_runtime.h>
#include <math.h>

#define N_NODES 100000
#define N_EDGES 1000000
#define HID     64
#define HIER    32
#define NDIM    128
#define EDIM    32
#define K1      96    // HIER + HID
#define C1      128   // 2*HID
#define NCLS    10
#define BN_EPS  1e-5f
#define SCAN_B  98    // ceil(N_NODES/1024)

// ---------------- CSR build ----------------

__global__ void k_count(const int* __restrict__ ei, int* __restrict__ cnt) {
    int i = blockIdx.x * blockDim.x + threadIdx.x;
    if (i < N_EDGES) atomicAdd(&cnt[ei[N_EDGES + i]], 1);
}

__global__ void k_scan1(const int* __restrict__ cnt, int* __restrict__ offs,
                        float* __restrict__ dinv, int* __restrict__ bsum) {
    __shared__ int buf[2][1024];
    int t = threadIdx.x, b = blockIdx.x;
    int i = b * 1024 + t;
    int v = (i < N_NODES) ? cnt[i] : 0;
    buf[0][t] = v; __syncthreads();
    int pi = 0;
    for (int off = 1; off < 1024; off <<= 1) {
        int x = buf[pi][t];
        if (t >= off) x += buf[pi][t - off];
        buf[pi ^ 1][t] = x; __syncthreads(); pi ^= 1;
    }
    int incl = buf[pi][t];
    if (i < N_NODES) {
        offs[i] = incl - v;                       // exclusive within block
        dinv[i] = rsqrtf((float)(v + 1));         // +1 self loop
    }
    if (t == 1023) bsum[b] = incl;
}

__global__ void k_scan2(int* __restrict__ bsum, int nb) {
    __shared__ int buf[2][1024];
    int t = threadIdx.x;
    int v = (t < nb) ? bsum[t] : 0;
    buf[0][t] = v; __syncthreads();
    int pi = 0;
    for (int off = 1; off < 1024; off <<= 1) {
        int x = buf[pi][t];
        if (t >= off) x += buf[pi][t - off];
        buf[pi ^ 1][t] = x; __syncthreads(); pi ^= 1;
    }
    int incl = buf[pi][t];
    if (t < nb) bsum[t] = incl - v;               // exclusive
}

__global__ void k_scan3(const int* __restrict__ bsum, int* __restrict__ offs) {
    int b = blockIdx.x;
    int i = b * 1024 + threadIdx.x;
    if (i < N_NODES) offs[i] += bsum[b];
    if (i == 0) offs[N_NODES] = N_EDGES;
}

__global__ void k_fill(const int* __restrict__ ei, const int* __restrict__ offs,
                       int* __restrict__ cursor, int* __restrict__ csr_src,
                       int* __restrict__ csr_eid) {
    int i = blockIdx.x * blockDim.x + threadIdx.x;
    if (i >= N_EDGES) return;
    int s = ei[i], d = ei[N_EDGES + i];
    int pos = offs[d] + atomicAdd(&cursor[d], 1);
    csr_src[pos] = s;
    csr_eid[pos] = i;
}

// ---------------- node encoder: h0 = x @ w_node + b ----------------

__global__ __launch_bounds__(256) void k_h0(const float* __restrict__ x,
                                            const float* __restrict__ w,
                                            const float* __restrict__ bias,
                                            float* __restrict__ h,
                                            float* __restrict__ hsum) {
    __shared__ float ws[NDIM * HID];  // 32 KB
    for (int i = threadIdx.x; i < NDIM * HID; i += 256) ws[i] = w[i];
    __syncthreads();
    int lane = threadIdx.x & 63, wid = threadIdx.x >> 6;
    float bl = bias[lane];
    for (int row = blockIdx.x * 4 + wid; row < N_NODES; row += gridDim.x * 4) {
        const float4* xr = (const float4*)(x + (size_t)row * NDIM);
        float acc = bl;
        #pragma unroll
        for (int k4 = 0; k4 < NDIM / 4; ++k4) {
            float4 xv = xr[k4];
            int k = k4 * 4;
            acc += xv.x * ws[(k + 0) * HID + lane];
            acc += xv.y * ws[(k + 1) * HID + lane];
            acc += xv.z * ws[(k + 2) * HID + lane];
            acc += xv.w * ws[(k + 3) * HID + lane];
        }
        h[(size_t)row * HID + lane] = acc;
        hsum[(size_t)row * HID + lane] = acc;
    }
}

// ---------------- edge aggregation: agg[v] = sum norm*e_raw, wsum[v] = sum norm ----------------

__global__ __launch_bounds__(256) void k_agg(const float* __restrict__ e,
                                             const int* __restrict__ csr_src,
                                             const int* __restrict__ csr_eid,
                                             const int* __restrict__ offs,
                                             const float* __restrict__ dinv,
                                             float* __restrict__ agg,
                                             float* __restrict__ wsumv) {
    int wid = threadIdx.x >> 6;
    int v = blockIdx.x * 4 + wid;
    if (v >= N_NODES) return;
    int lane = threadIdx.x & 63;
    int half = lane >> 5, dim = lane & 31;
    int start = offs[v], end = offs[v + 1];
    float dv = dinv[v];
    float acc = 0.f, wacc = 0.f;
    for (int i = start + half; i < end; i += 2) {
        int s = csr_src[i];
        int eid = csr_eid[i];
        float ds = dinv[s];
        acc += ds * e[(size_t)eid * EDIM + dim];
        wacc += ds;
    }
    acc += __shfl_xor(acc, 32);
    wacc += __shfl_xor(wacc, 32);
    if (half == 0) agg[(size_t)v * EDIM + dim] = dv * acc;
    if (lane == 0) wsumv[v] = dv * wacc;
}

// ---------------- s_e = agg @ w_edge + wsum * b_edge ----------------

__global__ __launch_bounds__(256) void k_se(const float* __restrict__ agg,
                                            const float* __restrict__ wsumv,
                                            const float* __restrict__ we,
                                            const float* __restrict__ be,
                                            float* __restrict__ se) {
    int lane = threadIdx.x & 63, wid = threadIdx.x >> 6;
    float wreg[EDIM];
    #pragma unroll
    for (int k = 0; k < EDIM; ++k) wreg[k] = we[k * HID + lane];
    float bl = be[lane];
    for (int v = blockIdx.x * 4 + wid; v < N_NODES; v += gridDim.x * 4) {
        const float4* ar = (const float4*)(agg + (size_t)v * EDIM);
        float acc = wsumv[v] * bl;
        #pragma unroll
        for (int k4 = 0; k4 < EDIM / 4; ++k4) {
            float4 av = ar[k4];
            int k = k4 * 4;
            acc += av.x * wreg[k + 0] + av.y * wreg[k + 1] +
                   av.z * wreg[k + 2] + av.w * wreg[k + 3];
        }
        se[(size_t)v * HID + lane] = acc;
    }
}

// ---------------- one GCN layer (pull) ----------------

__global__ __launch_bounds__(256) void k_layer(const float* __restrict__ hold,
                                               const float* __restrict__ se,
                                               const int* __restrict__ csr_src,
                                               const int* __restrict__ offs,
                                               const float* __restrict__ dinv,
                                               float* __restrict__ hnew,
                                               float* __restrict__ hsum) {
    int wid = threadIdx.x >> 6;
    int v = blockIdx.x * 4 + wid;
    if (v >= N_NODES) return;
    int lane = threadIdx.x & 63;
    int start = offs[v], end = offs[v + 1];
    float dv = dinv[v];
    size_t vi = (size_t)v * HID + lane;
    float acc = se[vi] + dv * dv * hold[vi];
    for (int i = start; i < end; ++i) {
        int s = csr_src[i];
        acc += dv * dinv[s] * hold[(size_t)s * HID + lane];
    }
    float hv = (acc > 0.f) ? acc : 0.2f * acc;
    hnew[vi] = hv;
    hsum[vi] += hv;
}

// ---------------- z row helper (z = [hsum|c] @ w_out1 + b_out1) ----------------

__device__ __forceinline__ void compute_z(const float* __restrict__ hsum,
                                          const float* __restrict__ c,
                                          const float* ws, float b0, float b1v,
                                          int v, int lane, float& z0, float& z1) {
    const float4* hr = (const float4*)(hsum + (size_t)v * HID);
    const float4* cr = (const float4*)(c + (size_t)v * HIER);
    float a0 = b0, a1 = b1v;
    #pragma unroll
    for (int k4 = 0; k4 < HID / 4; ++k4) {
        float4 xv = hr[k4];
        int k = k4 * 4;
        a0 += xv.x * ws[(k + 0) * C1 + lane];      a1 += xv.x * ws[(k + 0) * C1 + 64 + lane];
        a0 += xv.y * ws[(k + 1) * C1 + lane];      a1 += xv.y * ws[(k + 1) * C1 + 64 + lane];
        a0 += xv.z * ws[(k + 2) * C1 + lane];      a1 += xv.z * ws[(k + 2) * C1 + 64 + lane];
        a0 += xv.w * ws[(k + 3) * C1 + lane];      a1 += xv.w * ws[(k + 3) * C1 + 64 + lane];
    }
    #pragma unroll
    for (int k4 = 0; k4 < HIER / 4; ++k4) {
        float4 xv = cr[k4];
        int k = HID + k4 * 4;
        a0 += xv.x * ws[(k + 0) * C1 + lane];      a1 += xv.x * ws[(k + 0) * C1 + 64 + lane];
        a0 += xv.y * ws[(k + 1) * C1 + lane];      a1 += xv.y * ws[(k + 1) * C1 + 64 + lane];
        a0 += xv.z * ws[(k + 2) * C1 + lane];      a1 += xv.z * ws[(k + 2) * C1 + 64 + lane];
        a0 += xv.w * ws[(k + 3) * C1 + lane];      a1 += xv.w * ws[(k + 3) * C1 + 64 + lane];
    }
    z0 = a0; z1 = a1;
}

// ---------------- BN stats ----------------

__global__ __launch_bounds__(256) void k_stats(const float* __restrict__ hsum,
                                               const float* __restrict__ c,
                                               const float* __restrict__ w1,
                                               const float* __restrict__ b1,
                                               float* __restrict__ stats) {
    __shared__ float ws[K1 * C1];   // 48 KB
    __shared__ float red[4][C1];
    for (int i = threadIdx.x; i < K1 * C1; i += 256) ws[i] = w1[i];
    __syncthreads();
    int lane = threadIdx.x & 63, wid = threadIdx.x >> 6;
    float b0 = b1[lane], bb1 = b1[64 + lane];
    float s0 = 0.f, s1 = 0.f, q0 = 0.f, q1 = 0.f;
    for (int v = blockIdx.x * 4 + wid; v < N_NODES; v += gridDim.x * 4) {
        float z0, z1;
        compute_z(hsum, c, ws, b0, bb1, v, lane, z0, z1);
        s0 += z0; q0 += z0 * z0;
        s1 += z1; q1 += z1 * z1;
    }
    red[wid][lane] = s0; red[wid][64 + lane] = s1;
    __syncthreads();
    if (threadIdx.x < C1) {
        float t = red[0][threadIdx.x] + red[1][threadIdx.x] +
                  red[2][threadIdx.x] + red[3][threadIdx.x];
        atomicAdd(&stats[threadIdx.x], t);
    }
    __syncthreads();
    red[wid][lane] = q0; red[wid][64 + lane] = q1;
    __syncthreads();
    if (threadIdx.x < C1) {
        float t = red[0][threadIdx.x] + red[1][threadIdx.x] +
                  red[2][threadIdx.x] + red[3][threadIdx.x];
        atomicAdd(&stats[C1 + threadIdx.x], t);
    }
}

__global__ void k_ab(const float* __restrict__ stats, const float* __restrict__ gamma,
                     const float* __restrict__ beta, float* __restrict__ ab) {
    int t = threadIdx.x;
    if (t < C1) {
        float mu = stats[t] / (float)N_NODES;
        float var = stats[C1 + t] / (float)N_NODES - mu * mu;
        float inv = rsqrtf(var + BN_EPS);
        float a = gamma[t] * inv;
        ab[t] = a;
        ab[C1 + t] = beta[t] - mu * a;
    }
}

// ---------------- output: PReLU(BN(z)) @ w_out2 + b_out2 ----------------

__global__ __launch_bounds__(256) void k_out(const float* __restrict__ hsum,
                                             const float* __restrict__ c,
                                             const float* __restrict__ w1,
                                             const float* __restrict__ b1,
                                             const float* __restrict__ ab,
                                             const float* __restrict__ pa,
                                             const float* __restrict__ w2,
                                             const float* __restrict__ b2,
                                             float* __restrict__ out) {
    __shared__ float ws[K1 * C1];   // 48 KB
    for (int i = threadIdx.x; i < K1 * C1; i += 256) ws[i] = w1[i];
    __syncthreads();
    int lane = threadIdx.x & 63, wid = threadIdx.x >> 6;
    float w2a[NCLS], w2b[NCLS];
    #pragma unroll
    for (int j = 0; j < NCLS; ++j) {
        w2a[j] = w2[lane * NCLS + j];
        w2b[j] = w2[(64 + lane) * NCLS + j];
    }
    float b0 = b1[lane], bb1 = b1[64 + lane];
    float sa0 = ab[lane], sa1 = ab[64 + lane];
    float sb0 = ab[C1 + lane], sb1 = ab[C1 + 64 + lane];
    float alpha = pa[0];
    for (int v = blockIdx.x * 4 + wid; v < N_NODES; v += gridDim.x * 4) {
        float z0, z1;
        compute_z(hsum, c, ws, b0, bb1, v, lane, z0, z1);
        float p0 = z0 * sa0 + sb0; p0 = (p0 > 0.f) ? p0 : alpha * p0;
        float p1 = z1 * sa1 + sb1; p1 = (p1 > 0.f) ? p1 : alpha * p1;
        float pj[NCLS];
        #pragma unroll
        for (int j = 0; j < NCLS; ++j) pj[j] = p0 * w2a[j] + p1 * w2b[j];
        #pragma unroll
        for (int j = 0; j < NCLS; ++j) {
            #pragma unroll
            for (int d = 32; d >= 1; d >>= 1) pj[j] += __shfl_xor(pj[j], d);
        }
        if (lane == 0) {
            #pragma unroll
            for (int j = 0; j < NCLS; ++j) out[(size_t)v * NCLS + j] = pj[j] + b2[j];
        }
    }
}

// ---------------- host ----------------

extern "C" void kernel_launch(void* const* d_in, const int* in_sizes, int n_in,
                              void* d_out, int out_size, void* d_ws, size_t ws_size,
                              hipStream_t stream) {
    const float* x      = (const float*)d_in[0];
    const float* e      = (const float*)d_in[1];
    const float* c      = (const float*)d_in[2];
    const float* w_node = (const float*)d_in[3];
    const float* b_node = (const float*)d_in[4];
    const float* w_edge = (const float*)d_in[5];
    const float* b_edge = (const float*)d_in[6];
    const float* w_out1 = (const float*)d_in[7];
    const float* b_out1 = (const float*)d_in[8];
    const float* gamma  = (const float*)d_in[9];
    const float* beta   = (const float*)d_in[10];
    const float* pa     = (const float*)d_in[11];
    const float* w_out2 = (const float*)d_in[12];
    const float* b_out2 = (const float*)d_in[13];
    const int*   ei     = (const int*)d_in[14];
    float* out = (float*)d_out;

    char* wsb = (char*)d_ws;
    size_t off = 0;
    auto alloc = [&](size_t bytes) {
        void* p = wsb + off;
        off = (off + bytes + 255) & ~(size_t)255;
        return p;
    };
    int*   cnt     = (int*)alloc(4ull * N_NODES);
    int*   offs    = (int*)alloc(4ull * (N_NODES + 1));
    float* dinv    = (float*)alloc(4ull * N_NODES);
    int*   bsum    = (int*)alloc(4ull * 128);
    int*   csr_src = (int*)alloc(4ull * N_EDGES);
    int*   csr_eid = (int*)alloc(4ull * N_EDGES);
    float* agg     = (float*)alloc(4ull * N_NODES * EDIM);
    float* wsumv   = (float*)alloc(4ull * N_NODES);
    float* se      = (float*)alloc(4ull * N_NODES * HID);
    float* h_a     = (float*)alloc(4ull * N_NODES * HID);
    float* h_b     = (float*)alloc(4ull * N_NODES * HID);
    float* h_sum   = (float*)alloc(4ull * N_NODES * HID);
    float* stats   = (float*)alloc(4ull * 256);
    float* ab      = (float*)alloc(4ull * 256);

    hipMemsetAsync(cnt, 0, 4ull * N_NODES, stream);
    hipMemsetAsync(stats, 0, 4ull * 256, stream);

    k_count<<<(N_EDGES + 255) / 256, 256, 0, stream>>>(ei, cnt);
    k_scan1<<<SCAN_B, 1024, 0, stream>>>(cnt, offs, dinv, bsum);
    k_scan2<<<1, 1024, 0, stream>>>(bsum, SCAN_B);
    k_scan3<<<SCAN_B, 1024, 0, stream>>>(bsum, offs);
    hipMemsetAsync(cnt, 0, 4ull * N_NODES, stream);
    k_fill<<<(N_EDGES + 255) / 256, 256, 0, stream>>>(ei, offs, cnt, csr_src, csr_eid);

    k_h0<<<1280, 256, 0, stream>>>(x, w_node, b_node, h_a, h_sum);
    k_agg<<<N_NODES / 4, 256, 0, stream>>>(e, csr_src, csr_eid, offs, dinv, agg, wsumv);
    k_se<<<1280, 256, 0, stream>>>(agg, wsumv, w_edge, b_edge, se);

    k_layer<<<N_NODES / 4, 256, 0, stream>>>(h_a, se, csr_src, offs, dinv, h_b, h_sum);
    k_layer<<<N_NODES / 4, 256, 0, stream>>>(h_b, se, csr_src, offs, dinv, h_a, h_sum);
    k_layer<<<N_NODES / 4, 256, 0, stream>>>(h_a, se, csr_src, offs, dinv, h_b, h_sum);

    k_stats<<<512, 256, 0, stream>>>(h_sum, c, w_out1, b_out1, stats);
    k_ab<<<1, 128, 0, stream>>>(stats, gamma, beta, ab);
    k_out<<<512, 256, 0, stream>>>(h_sum, c, w_out1, b_out1, ab, pa, w_out2, b_out2, out);
}

// Round 2
// 1010.488 us; speedup vs baseline: 1.0040x; 1.0040x over previous
//
#include <hip/hip_runtime.h>
#include <math.h>

#define N_NODES 100000
#define N_EDGES 1000000
#define HID     64
#define HIER    32
#define NDIM    128
#define EDIM    32
#define K1      96    // HIER + HID
#define C1      128   // 2*HID
#define NCLS    10
#define BN_EPS  1e-5f
#define SCAN_B  98    // ceil(N_NODES/1024)

// ---------------- CSR build ----------------

__global__ void k_count(const int* __restrict__ ei, int* __restrict__ cnt) {
    int i = blockIdx.x * blockDim.x + threadIdx.x;
    if (i < N_EDGES) atomicAdd(&cnt[ei[N_EDGES + i]], 1);
}

__global__ void k_scan1(const int* __restrict__ cnt, int* __restrict__ offs,
                        float* __restrict__ dinv, int* __restrict__ bsum) {
    __shared__ int buf[2][1024];
    int t = threadIdx.x, b = blockIdx.x;
    int i = b * 1024 + t;
    int v = (i < N_NODES) ? cnt[i] : 0;
    buf[0][t] = v; __syncthreads();
    int pi = 0;
    for (int off = 1; off < 1024; off <<= 1) {
        int x = buf[pi][t];
        if (t >= off) x += buf[pi][t - off];
        buf[pi ^ 1][t] = x; __syncthreads(); pi ^= 1;
    }
    int incl = buf[pi][t];
    if (i < N_NODES) {
        offs[i] = incl - v;                       // exclusive within block
        dinv[i] = rsqrtf((float)(v + 1));         // +1 self loop
    }
    if (t == 1023) bsum[b] = incl;
}

__global__ void k_scan2(int* __restrict__ bsum, int nb) {
    __shared__ int buf[2][1024];
    int t = threadIdx.x;
    int v = (t < nb) ? bsum[t] : 0;
    buf[0][t] = v; __syncthreads();
    int pi = 0;
    for (int off = 1; off < 1024; off <<= 1) {
        int x = buf[pi][t];
        if (t >= off) x += buf[pi][t - off];
        buf[pi ^ 1][t] = x; __syncthreads(); pi ^= 1;
    }
    int incl = buf[pi][t];
    if (t < nb) bsum[t] = incl - v;               // exclusive
}

__global__ void k_scan3(const int* __restrict__ bsum, int* __restrict__ offs) {
    int b = blockIdx.x;
    int i = b * 1024 + threadIdx.x;
    if (i < N_NODES) offs[i] += bsum[b];
    if (i == 0) offs[N_NODES] = N_EDGES;
}

__global__ void k_fill(const int* __restrict__ ei, const int* __restrict__ offs,
                       int* __restrict__ cursor, int* __restrict__ csr_src,
                       int* __restrict__ csr_eid) {
    int i = blockIdx.x * blockDim.x + threadIdx.x;
    if (i >= N_EDGES) return;
    int s = ei[i], d = ei[N_EDGES + i];
    int pos = offs[d] + atomicAdd(&cursor[d], 1);
    csr_src[pos] = s;
    csr_eid[pos] = i;
}

// ---------------- node encoder: h0 = x @ w_node + b ----------------

__global__ __launch_bounds__(256) void k_h0(const float* __restrict__ x,
                                            const float* __restrict__ w,
                                            const float* __restrict__ bias,
                                            float* __restrict__ h,
                                            float* __restrict__ hsum) {
    __shared__ float ws[NDIM * HID];  // 32 KB
    for (int i = threadIdx.x; i < NDIM * HID; i += 256) ws[i] = w[i];
    __syncthreads();
    int lane = threadIdx.x & 63, wid = threadIdx.x >> 6;
    float bl = bias[lane];
    for (int row = blockIdx.x * 4 + wid; row < N_NODES; row += gridDim.x * 4) {
        const float4* xr = (const float4*)(x + (size_t)row * NDIM);
        float acc = bl;
        #pragma unroll
        for (int k4 = 0; k4 < NDIM / 4; ++k4) {
            float4 xv = xr[k4];
            int k = k4 * 4;
            acc += xv.x * ws[(k + 0) * HID + lane];
            acc += xv.y * ws[(k + 1) * HID + lane];
            acc += xv.z * ws[(k + 2) * HID + lane];
            acc += xv.w * ws[(k + 3) * HID + lane];
        }
        h[(size_t)row * HID + lane] = acc;
        hsum[(size_t)row * HID + lane] = acc;
    }
}

// ---------------- edge aggregation: agg[v] = sum norm*e_raw, wsum[v] = sum norm ----------------

__global__ __launch_bounds__(256) void k_agg(const float* __restrict__ e,
                                             const int* __restrict__ csr_src,
                                             const int* __restrict__ csr_eid,
                                             const int* __restrict__ offs,
                                             const float* __restrict__ dinv,
                                             float* __restrict__ agg,
                                             float* __restrict__ wsumv) {
    int wid = threadIdx.x >> 6;
    int v = blockIdx.x * 4 + wid;
    if (v >= N_NODES) return;
    int lane = threadIdx.x & 63;
    int half = lane >> 5, dim = lane & 31;
    int start = offs[v], end = offs[v + 1];
    float dv = dinv[v];
    float acc = 0.f, wacc = 0.f;
    for (int i = start + half; i < end; i += 2) {
        int s = csr_src[i];
        int eid = csr_eid[i];
        float ds = dinv[s];
        acc += ds * e[(size_t)eid * EDIM + dim];
        wacc += ds;
    }
    acc += __shfl_xor(acc, 32);
    wacc += __shfl_xor(wacc, 32);
    if (half == 0) agg[(size_t)v * EDIM + dim] = dv * acc;
    if (lane == 0) wsumv[v] = dv * wacc;
}

// ---------------- s_e = agg @ w_edge + wsum * b_edge ----------------

__global__ __launch_bounds__(256) void k_se(const float* __restrict__ agg,
                                            const float* __restrict__ wsumv,
                                            const float* __restrict__ we,
                                            const float* __restrict__ be,
                                            float* __restrict__ se) {
    int lane = threadIdx.x & 63, wid = threadIdx.x >> 6;
    float wreg[EDIM];
    #pragma unroll
    for (int k = 0; k < EDIM; ++k) wreg[k] = we[k * HID + lane];
    float bl = be[lane];
    for (int v = blockIdx.x * 4 + wid; v < N_NODES; v += gridDim.x * 4) {
        const float4* ar = (const float4*)(agg + (size_t)v * EDIM);
        float acc = wsumv[v] * bl;
        #pragma unroll
        for (int k4 = 0; k4 < EDIM / 4; ++k4) {
            float4 av = ar[k4];
            int k = k4 * 4;
            acc += av.x * wreg[k + 0] + av.y * wreg[k + 1] +
                   av.z * wreg[k + 2] + av.w * wreg[k + 3];
        }
        se[(size_t)v * HID + lane] = acc;
    }
}

// ---------------- one GCN layer (pull) ----------------

__global__ __launch_bounds__(256) void k_layer(const float* __restrict__ hold,
                                               const float* __restrict__ se,
                                               const int* __restrict__ csr_src,
                                               const int* __restrict__ offs,
                                               const float* __restrict__ dinv,
                                               float* __restrict__ hnew,
                                               float* __restrict__ hsum) {
    int wid = threadIdx.x >> 6;
    int v = blockIdx.x * 4 + wid;
    if (v >= N_NODES) return;
    int lane = threadIdx.x & 63;
    int start = offs[v], end = offs[v + 1];
    float dv = dinv[v];
    size_t vi = (size_t)v * HID + lane;
    float acc = se[vi] + dv * dv * hold[vi];
    for (int i = start; i < end; ++i) {
        int s = csr_src[i];
        acc += dv * dinv[s] * hold[(size_t)s * HID + lane];
    }
    float hv = (acc > 0.f) ? acc : 0.2f * acc;
    hnew[vi] = hv;
    hsum[vi] += hv;
}

// ---------------- z row helper (z = [hsum|c] @ w_out1 + b_out1) ----------------

__device__ __forceinline__ void compute_z(const float* __restrict__ hsum,
                                          const float* __restrict__ c,
                                          const float* ws, float b0, float b1v,
                                          int v, int lane, float& z0, float& z1) {
    const float4* hr = (const float4*)(hsum + (size_t)v * HID);
    const float4* cr = (const float4*)(c + (size_t)v * HIER);
    float a0 = b0, a1 = b1v;
    #pragma unroll
    for (int k4 = 0; k4 < HID / 4; ++k4) {
        float4 xv = hr[k4];
        int k = k4 * 4;
        a0 += xv.x * ws[(k + 0) * C1 + lane];      a1 += xv.x * ws[(k + 0) * C1 + 64 + lane];
        a0 += xv.y * ws[(k + 1) * C1 + lane];      a1 += xv.y * ws[(k + 1) * C1 + 64 + lane];
        a0 += xv.z * ws[(k + 2) * C1 + lane];      a1 += xv.z * ws[(k + 2) * C1 + 64 + lane];
        a0 += xv.w * ws[(k + 3) * C1 + lane];      a1 += xv.w * ws[(k + 3) * C1 + 64 + lane];
    }
    #pragma unroll
    for (int k4 = 0; k4 < HIER / 4; ++k4) {
        float4 xv = cr[k4];
        int k = HID + k4 * 4;
        a0 += xv.x * ws[(k + 0) * C1 + lane];      a1 += xv.x * ws[(k + 0) * C1 + 64 + lane];
        a0 += xv.y * ws[(k + 1) * C1 + lane];      a1 += xv.y * ws[(k + 1) * C1 + 64 + lane];
        a0 += xv.z * ws[(k + 2) * C1 + lane];      a1 += xv.z * ws[(k + 2) * C1 + 64 + lane];
        a0 += xv.w * ws[(k + 3) * C1 + lane];      a1 += xv.w * ws[(k + 3) * C1 + 64 + lane];
    }
    z0 = a0; z1 = a1;
}

// ---------------- BN stats ----------------

__global__ __launch_bounds__(256) void k_stats(const float* __restrict__ hsum,
                                               const float* __restrict__ c,
                                               const float* __restrict__ w1,
                                               const float* __restrict__ b1,
                                               float* __restrict__ stats) {
    __shared__ float ws[K1 * C1];   // 48 KB
    __shared__ float red[4][C1];
    for (int i = threadIdx.x; i < K1 * C1; i += 256) ws[i] = w1[i];
    __syncthreads();
    int lane = threadIdx.x & 63, wid = threadIdx.x >> 6;
    float b0 = b1[lane], bb1 = b1[64 + lane];
    float s0 = 0.f, s1 = 0.f, q0 = 0.f, q1 = 0.f;
    for (int v = blockIdx.x * 4 + wid; v < N_NODES; v += gridDim.x * 4) {
        float z0, z1;
        compute_z(hsum, c, ws, b0, bb1, v, lane, z0, z1);
        s0 += z0; q0 += z0 * z0;
        s1 += z1; q1 += z1 * z1;
    }
    red[wid][lane] = s0; red[wid][64 + lane] = s1;
    __syncthreads();
    if (threadIdx.x < C1) {
        float t = red[0][threadIdx.x] + red[1][threadIdx.x] +
                  red[2][threadIdx.x] + red[3][threadIdx.x];
        atomicAdd(&stats[threadIdx.x], t);
    }
    __syncthreads();
    red[wid][lane] = q0; red[wid][64 + lane] = q1;
    __syncthreads();
    if (threadIdx.x < C1) {
        float t = red[0][threadIdx.x] + red[1][threadIdx.x] +
                  red[2][threadIdx.x] + red[3][threadIdx.x];
        atomicAdd(&stats[C1 + threadIdx.x], t);
    }
}

__global__ void k_ab(const float* __restrict__ stats, const float* __restrict__ gamma,
                     const float* __restrict__ beta, float* __restrict__ ab) {
    int t = threadIdx.x;
    if (t < C1) {
        float mu = stats[t] / (float)N_NODES;
        float var = stats[C1 + t] / (float)N_NODES - mu * mu;
        float inv = rsqrtf(var + BN_EPS);
        float a = gamma[t] * inv;
        ab[t] = a;
        ab[C1 + t] = beta[t] - mu * a;
    }
}

// ---------------- output: PReLU(BN(z)) @ w_out2 + b_out2 ----------------

__global__ __launch_bounds__(256) void k_out(const float* __restrict__ hsum,
                                             const float* __restrict__ c,
                                             const float* __restrict__ w1,
                                             const float* __restrict__ b1,
                                             const float* __restrict__ ab,
                                             const float* __restrict__ pa,
                                             const float* __restrict__ w2,
                                             const float* __restrict__ b2,
                                             float* __restrict__ out) {
    __shared__ float ws[K1 * C1];   // 48 KB
    for (int i = threadIdx.x; i < K1 * C1; i += 256) ws[i] = w1[i];
    __syncthreads();
    int lane = threadIdx.x & 63, wid = threadIdx.x >> 6;
    float w2a[NCLS], w2b[NCLS];
    #pragma unroll
    for (int j = 0; j < NCLS; ++j) {
        w2a[j] = w2[lane * NCLS + j];
        w2b[j] = w2[(64 + lane) * NCLS + j];
    }
    float b0 = b1[lane], bb1 = b1[64 + lane];
    float sa0 = ab[lane], sa1 = ab[64 + lane];
    float sb0 = ab[C1 + lane], sb1 = ab[C1 + 64 + lane];
    float alpha = pa[0];
    for (int v = blockIdx.x * 4 + wid; v < N_NODES; v += gridDim.x * 4) {
        float z0, z1;
        compute_z(hsum, c, ws, b0, bb1, v, lane, z0, z1);
        float p0 = z0 * sa0 + sb0; p0 = (p0 > 0.f) ? p0 : alpha * p0;
        float p1 = z1 * sa1 + sb1; p1 = (p1 > 0.f) ? p1 : alpha * p1;
        float pj[NCLS];
        #pragma unroll
        for (int j = 0; j < NCLS; ++j) pj[j] = p0 * w2a[j] + p1 * w2b[j];
        #pragma unroll
        for (int j = 0; j < NCLS; ++j) {
            #pragma unroll
            for (int d = 32; d >= 1; d >>= 1) pj[j] += __shfl_xor(pj[j], d);
        }
        if (lane == 0) {
            #pragma unroll
            for (int j = 0; j < NCLS; ++j) out[(size_t)v * NCLS + j] = pj[j] + b2[j];
        }
    }
}

// ---------------- host ----------------

extern "C" void kernel_launch(void* const* d_in, const int* in_sizes, int n_in,
                              void* d_out, int out_size, void* d_ws, size_t ws_size,
                              hipStream_t stream) {
    const float* x      = (const float*)d_in[0];
    const float* e      = (const float*)d_in[1];
    const float* c      = (const float*)d_in[2];
    const float* w_node = (const float*)d_in[3];
    const float* b_node = (const float*)d_in[4];
    const float* w_edge = (const float*)d_in[5];
    const float* b_edge = (const float*)d_in[6];
    const float* w_out1 = (const float*)d_in[7];
    const float* b_out1 = (const float*)d_in[8];
    const float* gamma  = (const float*)d_in[9];
    const float* beta   = (const float*)d_in[10];
    const float* pa     = (const float*)d_in[11];
    const float* w_out2 = (const float*)d_in[12];
    const float* b_out2 = (const float*)d_in[13];
    const int*   ei     = (const int*)d_in[14];
    float* out = (float*)d_out;

    char* wsb = (char*)d_ws;
    size_t off = 0;
    auto alloc = [&](size_t bytes) {
        void* p = wsb + off;
        off = (off + bytes + 255) & ~(size_t)255;
        return p;
    };
    int*   cnt     = (int*)alloc(4ull * N_NODES);
    int*   offs    = (int*)alloc(4ull * (N_NODES + 1));
    float* dinv    = (float*)alloc(4ull * N_NODES);
    int*   bsum    = (int*)alloc(4ull * 128);
    int*   csr_src = (int*)alloc(4ull * N_EDGES);
    int*   csr_eid = (int*)alloc(4ull * N_EDGES);
    float* agg     = (float*)alloc(4ull * N_NODES * EDIM);
    float* wsumv   = (float*)alloc(4ull * N_NODES);
    float* se      = (float*)alloc(4ull * N_NODES * HID);
    float* h_a     = (float*)alloc(4ull * N_NODES * HID);
    float* h_b     = (float*)alloc(4ull * N_NODES * HID);
    float* h_sum   = (float*)alloc(4ull * N_NODES * HID);
    float* stats   = (float*)alloc(4ull * 256);
    float* ab      = (float*)alloc(4ull * 256);

    hipMemsetAsync(cnt, 0, 4ull * N_NODES, stream);
    hipMemsetAsync(stats, 0, 4ull * 256, stream);

    k_count<<<(N_EDGES + 255) / 256, 256, 0, stream>>>(ei, cnt);
    k_scan1<<<SCAN_B, 1024, 0, stream>>>(cnt, offs, dinv, bsum);
    k_scan2<<<1, 1024, 0, stream>>>(bsum, SCAN_B);
    k_scan3<<<SCAN_B, 1024, 0, stream>>>(bsum, offs);
    hipMemsetAsync(cnt, 0, 4ull * N_NODES, stream);
    k_fill<<<(N_EDGES + 255) / 256, 256, 0, stream>>>(ei, offs, cnt, csr_src, csr_eid);

    k_h0<<<1280, 256, 0, stream>>>(x, w_node, b_node, h_a, h_sum);
    k_agg<<<N_NODES / 4, 256, 0, stream>>>(e, csr_src, csr_eid, offs, dinv, agg, wsumv);
    k_se<<<1280, 256, 0, stream>>>(agg, wsumv, w_edge, b_edge, se);

    k_layer<<<N_NODES / 4, 256, 0, stream>>>(h_a, se, csr_src, offs, dinv, h_b, h_sum);
    k_layer<<<N_NODES / 4, 256, 0, stream>>>(h_b, se, csr_src, offs, dinv, h_a, h_sum);
    k_layer<<<N_NODES / 4, 256, 0, stream>>>(h_a, se, csr_src, offs, dinv, h_b, h_sum);

    k_stats<<<512, 256, 0, stream>>>(h_sum, c, w_out1, b_out1, stats);
    k_ab<<<1, 128, 0, stream>>>(stats, gamma, beta, ab);
    k_out<<<512, 256, 0, stream>>>(h_sum, c, w_out1, b_out1, ab, pa, w_out2, b_out2, out);
}